// Round 5
// baseline (707.279 us; speedup 1.0000x reference)
//
#include <hip/hip_runtime.h>

#define NS 200000
#define NK 27
#define NBLK 782   // ceil(NS/256)
#define EPSV 1e-5f

typedef __bf16 bf16x8 __attribute__((ext_vector_type(8)));
typedef float f32x4 __attribute__((ext_vector_type(4)));
typedef unsigned short u16;
typedef u16 u16x8 __attribute__((ext_vector_type(8)));
typedef u16 u16x4 __attribute__((ext_vector_type(4)));
typedef unsigned u32;

__device__ __forceinline__ u16 f2bf(float f) {
  union { float f; unsigned u; } v; v.f = f;
  unsigned r = v.u + 0x7fffu + ((v.u >> 16) & 1u);
  return (u16)(r >> 16);
}
__device__ __forceinline__ float bf2f(u16 u) {
  union { unsigned u; float f; } v; v.u = ((unsigned)u) << 16;
  return v.f;
}

// ---- prep: zero stats, feats f32 -> bf16 with zero row at N ----
__global__ void k_prep_x(const float* __restrict__ feats, u16* __restrict__ Xbf,
                         float* __restrict__ stats) {
  long i = (long)blockIdx.x * 256 + threadIdx.x;
  if (i < 768) stats[i] = 0.f;
  const long total = (long)(NS + 1) * 64;
  if (i < total) {
    long row = i >> 6;
    Xbf[i] = (row < NS) ? f2bf(feats[i]) : (u16)0;
  }
}

// ---- fused gather index: gidx = valid ? in_idx : NS ----
__global__ void k_prep_gidx(const int* __restrict__ in_idx, const int* __restrict__ out_idx,
                            int* __restrict__ gidx) {
  long i = (long)blockIdx.x * 256 + threadIdx.x;
  if (i < (long)NK * NS) gidx[i] = (out_idx[i] != NS) ? in_idx[i] : NS;
}

// ---- pack W [K][C][128] f32 -> lane-linear MFMA-B-fragment bf16 ----
// packed f = ((k*S+s)*8+cf)*512 + l*8 + j  <->  W[k][s*32+(l>>4)*8+j][cf*16+(l&15)]
// Lane l reads bytes [l*16, l*16+16) of each 1024B fragment block:
// ds_read_b128 is conflict-free and global reads are perfectly coalesced.
__global__ void k_pack_w(const float* __restrict__ W1, const float* __restrict__ W2,
                         const float* __restrict__ Wsc, u16* __restrict__ Wp1,
                         u16* __restrict__ Wp2, u16* __restrict__ Wpsc) {
  int i = blockIdx.x * 256 + threadIdx.x;
  const int n1 = NK * 64 * 128, n2 = NK * 128 * 128, n3 = 64 * 128;
  const float* src; u16* dst; int f, S, C;
  if (i < n1)            { src = W1;  dst = Wp1;  f = i;            S = 2; C = 64; }
  else if (i < n1 + n2)  { src = W2;  dst = Wp2;  f = i - n1;       S = 4; C = 128; }
  else if (i < n1 + n2 + n3) { src = Wsc; dst = Wpsc; f = i - n1 - n2; S = 2; C = 64; }
  else return;
  int j = f & 7, l = (f >> 3) & 63, cf = (f >> 9) & 7;
  int rest = f >> 12;
  int s = rest % S, k = rest / S;
  int kk = s * 32 + (l >> 4) * 8 + j;
  dst[f] = f2bf(src[(k * C + kk) * 128 + cf * 16 + (l & 15)]);
}

// ---- gather-GEMM conv: 8 waves x 32 rows = 256 rows/block; W staged in LDS
// (dbuf, global_load_lds, lane-linear), A gathered per-lane from global,
// counted-vmcnt raw barriers (no full drains in loop) ----
template <int C, bool FUSE_SC>
__global__ __launch_bounds__(512, 4) void k_conv(
    const u16* __restrict__ X, const u16* __restrict__ Wp, const u16* __restrict__ Wpsc,
    const int* __restrict__ gidx,
    u16* __restrict__ Y, u16* __restrict__ SCb, float* __restrict__ partial) {
  constexpr int S = C / 32;             // K-slices of 32
  constexpr int SLICE = C * 128;        // u16 elems per packed k-slice
  constexpr int NST = SLICE / 4096;     // global_load_lds issues per wave per k
  constexpr int NG = 2 * S;             // gather loads per wave per k
  constexpr int NW_STEADY = NG + 2 + NST + NG + 2;
  constexpr int PC = FUSE_SC ? 512 : 256;
  __shared__ alignas(16) u16 Wbuf[2 * SLICE];
  __shared__ float red[2048];

  const int t = threadIdx.x, w = t >> 6, l = t & 63;
  const int lr = l & 15, lh = l >> 4;
  const int rowbase = blockIdx.x * 256 + w * 32;
  const int laneoff = l * 8;

  int rr[2]; bool ok[2]; long rc[2];
  #pragma unroll
  for (int m = 0; m < 2; ++m) {
    rr[m] = rowbase + m * 16 + lr;
    ok[m] = rr[m] < NS;
    rc[m] = ok[m] ? rr[m] : 0;
  }

  auto stage = [&](int k, int bsel) {
    #pragma unroll
    for (int i = 0; i < NST; ++i) {
      const u16* g = Wp + (long)k * SLICE + (w * NST + i) * 512 + l * 8;
      u16* d = &Wbuf[bsel * SLICE + (w * NST + i) * 512];
      __builtin_amdgcn_global_load_lds(
          (const __attribute__((address_space(1))) u32*)g,
          (__attribute__((address_space(3))) u32*)d, 16, 0, 0);
    }
  };
  auto loadidx = [&](int k, int (&dst)[2]) {
    #pragma unroll
    for (int m = 0; m < 2; ++m) {
      int v = gidx[(long)k * NS + rc[m]];
      dst[m] = ok[m] ? v : NS;
    }
  };
  auto gather = [&](const int (&src)[2], bf16x8 (&a)[2][S]) {
    #pragma unroll
    for (int m = 0; m < 2; ++m) {
      const u16* rowp = X + (long)src[m] * C + lh * 8;
      #pragma unroll
      for (int s = 0; s < S; ++s)
        a[m][s] = *reinterpret_cast<const bf16x8*>(rowp + s * 32);
    }
  };
  auto compute = [&](int bsel, const bf16x8 (&a)[2][S], f32x4 (&ac)[2][8]) {
    __builtin_amdgcn_s_setprio(1);
    #pragma unroll
    for (int s = 0; s < S; ++s)
      #pragma unroll
      for (int cf = 0; cf < 8; ++cf) {
        bf16x8 b = *reinterpret_cast<const bf16x8*>(&Wbuf[bsel * SLICE + (s * 8 + cf) * 512 + laneoff]);
        ac[0][cf] = __builtin_amdgcn_mfma_f32_16x16x32_bf16(a[0][s], b, ac[0][cf], 0, 0, 0);
        ac[1][cf] = __builtin_amdgcn_mfma_f32_16x16x32_bf16(a[1][s], b, ac[1][cf], 0, 0, 0);
      }
    __builtin_amdgcn_s_setprio(0);
  };
  auto emit = [&](f32x4 (&ac)[2][8], u16* __restrict__ Yp, int poff) {
    #pragma unroll
    for (int m = 0; m < 2; ++m)
      #pragma unroll
      for (int cf = 0; cf < 8; ++cf) {
        int ch = cf * 16 + lr;
        #pragma unroll
        for (int r = 0; r < 4; ++r) {
          long row = rowbase + m * 16 + lh * 4 + r;
          if (row < NS) Yp[row * 128 + ch] = f2bf(ac[m][cf][r]);
        }
      }
    #pragma unroll
    for (int cf = 0; cf < 8; ++cf) {
      float s = 0.f, q = 0.f;
      #pragma unroll
      for (int m = 0; m < 2; ++m)
        #pragma unroll
        for (int r = 0; r < 4; ++r) { float v = ac[m][cf][r]; s += v; q += v * v; }
      s += __shfl_xor(s, 16); s += __shfl_xor(s, 32);
      q += __shfl_xor(q, 16); q += __shfl_xor(q, 32);
      if (lh == 0) {
        red[w * 256 + cf * 16 + lr] = s;
        red[w * 256 + 128 + cf * 16 + lr] = q;
      }
    }
    __syncthreads();
    if (t < 256) {
      float sum = 0.f;
      #pragma unroll
      for (int wi = 0; wi < 8; ++wi) sum += red[wi * 256 + t];
      partial[(long)blockIdx.x * PC + poff + t] = sum;
    }
    __syncthreads();
  };

  // ---- pipeline prologue ----
  int sv0[2], sv1[2];
  bf16x8 av0[2][S], av1[2][S];
  loadidx(0, sv0);
  stage(0, 0);
  gather(sv0, av0);
  loadidx(1, sv1);

  if constexpr (FUSE_SC) {
    // shortcut: identity gather of own rows, B-frags direct from global (one-time)
    bf16x8 ai[2][S];
    #pragma unroll
    for (int m = 0; m < 2; ++m) {
      long srcr = ok[m] ? rr[m] : NS;
      #pragma unroll
      for (int s = 0; s < S; ++s)
        ai[m][s] = *reinterpret_cast<const bf16x8*>(X + srcr * C + lh * 8 + s * 32);
    }
    f32x4 asc[2][8];
    #pragma unroll
    for (int m = 0; m < 2; ++m)
      #pragma unroll
      for (int cf = 0; cf < 8; ++cf) asc[m][cf] = (f32x4){0.f, 0.f, 0.f, 0.f};
    #pragma unroll
    for (int s = 0; s < S; ++s)
      #pragma unroll
      for (int cf = 0; cf < 8; ++cf) {
        bf16x8 b = *reinterpret_cast<const bf16x8*>(Wpsc + (s * 8 + cf) * 512 + laneoff);
        asc[0][cf] = __builtin_amdgcn_mfma_f32_16x16x32_bf16(ai[0][s], b, asc[0][cf], 0, 0, 0);
        asc[1][cf] = __builtin_amdgcn_mfma_f32_16x16x32_bf16(ai[1][s], b, asc[1][cf], 0, 0, 0);
      }
    emit(asc, SCb, 256);  // ends with full drain -> loop-entry waits trivially safe
  }

  f32x4 acc[2][8];
  #pragma unroll
  for (int m = 0; m < 2; ++m)
    #pragma unroll
    for (int cf = 0; cf < 8; ++cf) acc[m][cf] = (f32x4){0.f, 0.f, 0.f, 0.f};

  // ---- main loop: double-step k, k+1 (static buffer/reg parity) ----
  #pragma unroll 1
  for (int k = 0; k < 24; k += 2) {
    stage(k + 1, 1);
    gather(sv1, av1);
    loadidx(k + 2, sv0);
    asm volatile("s_waitcnt vmcnt(%0)\n\ts_barrier" :: "i"(NW_STEADY) : "memory");
    compute(0, av0, acc);
    asm volatile("s_waitcnt lgkmcnt(0)\n\ts_barrier" ::: "memory");

    stage(k + 2, 0);
    gather(sv0, av0);
    loadidx(k + 3, sv1);
    asm volatile("s_waitcnt vmcnt(%0)\n\ts_barrier" :: "i"(NW_STEADY) : "memory");
    compute(1, av1, acc);
    asm volatile("s_waitcnt lgkmcnt(0)\n\ts_barrier" ::: "memory");
  }
  // ---- peeled k=24,25,26 with exact tail counts ----
  stage(25, 1);
  gather(sv1, av1);
  loadidx(26, sv0);
  asm volatile("s_waitcnt vmcnt(%0)\n\ts_barrier" :: "i"(NW_STEADY) : "memory");
  compute(0, av0, acc);
  asm volatile("s_waitcnt lgkmcnt(0)\n\ts_barrier" ::: "memory");

  stage(26, 0);
  gather(sv0, av0);
  asm volatile("s_waitcnt vmcnt(%0)\n\ts_barrier" :: "i"(NW_STEADY - 2) : "memory");
  compute(1, av1, acc);
  asm volatile("s_waitcnt lgkmcnt(0)\n\ts_barrier" ::: "memory");

  asm volatile("s_waitcnt vmcnt(%0)\n\ts_barrier" :: "i"(NG) : "memory");
  compute(0, av0, acc);

  emit(acc, Y, 0);
}

// ---- deterministic 2-stage partial reduce ----
__global__ void k_red1(const float* __restrict__ part, float* __restrict__ tmp,
                       int pc, int nrows) {
  int c = blockIdx.x * 256 + threadIdx.x;
  float s = 0.f;
  for (int r = blockIdx.y; r < nrows; r += 32) s += part[(long)r * pc + c];
  tmp[(long)blockIdx.y * pc + c] = s;
}
__global__ void k_red2(const float* __restrict__ tmp, float* __restrict__ out, int pc) {
  int c = blockIdx.x * 256 + threadIdx.x;
  float s = 0.f;
  #pragma unroll
  for (int r = 0; r < 32; ++r) s += tmp[(long)r * pc + c];
  out[c] = s;
}

// ---- h = relu(bn1(y1)) -> bf16 (+ zero dummy row N) ----
__global__ void k_bnrelu(const u16* __restrict__ Y1, const float* __restrict__ stats,
                         const float* __restrict__ g, const float* __restrict__ b,
                         u16* __restrict__ H) {
  long i8 = (long)blockIdx.x * 256 + threadIdx.x;
  const long tot = (long)(NS + 1) * 16;
  if (i8 >= tot) return;
  long row = i8 >> 4;
  u16x8 o;
  if (row < NS) {
    int ch0 = ((int)i8 & 15) * 8;
    u16x8 y = *reinterpret_cast<const u16x8*>(Y1 + i8 * 8);
    #pragma unroll
    for (int e = 0; e < 8; ++e) {
      int ch = ch0 + e;
      float m = stats[ch] * (1.f / NS);
      float var = stats[128 + ch] * (1.f / NS) - m * m;
      float a = g[ch] * rsqrtf(var + EPSV);
      float bb = b[ch] - m * a;
      float h = bf2f(y[e]) * a + bb;
      o[e] = f2bf(h > 0.f ? h : 0.f);
    }
  } else {
    #pragma unroll
    for (int e = 0; e < 8; ++e) o[e] = (u16)0;
  }
  *reinterpret_cast<u16x8*>(H + i8 * 8) = o;
}

// ---- out = relu(bn2(y2) + bnsc(sc)) f32 ----
__global__ void k_final(const u16* __restrict__ Y2, const u16* __restrict__ SCb,
                        const float* __restrict__ stats,
                        const float* __restrict__ g2, const float* __restrict__ b2,
                        const float* __restrict__ gsc, const float* __restrict__ bsc,
                        float* __restrict__ out) {
  long i4 = (long)blockIdx.x * 256 + threadIdx.x;
  if (i4 >= (long)NS * 32) return;
  int ch0 = ((int)i4 & 31) * 4;
  u16x4 y = *reinterpret_cast<const u16x4*>(Y2 + i4 * 4);
  u16x4 s = *reinterpret_cast<const u16x4*>(SCb + i4 * 4);
  f32x4 o;
  #pragma unroll
  for (int e = 0; e < 4; ++e) {
    int ch = ch0 + e;
    float m2 = stats[512 + ch] * (1.f / NS);
    float v2 = stats[640 + ch] * (1.f / NS) - m2 * m2;
    float a2 = g2[ch] * rsqrtf(v2 + EPSV);
    float msc = stats[256 + ch] * (1.f / NS);
    float vsc = stats[384 + ch] * (1.f / NS) - msc * msc;
    float asc = gsc[ch] * rsqrtf(vsc + EPSV);
    float val = bf2f(y[e]) * a2 + (b2[ch] - m2 * a2)
              + bf2f(s[e]) * asc + (bsc[ch] - msc * asc);
    o[e] = val > 0.f ? val : 0.f;
  }
  *reinterpret_cast<f32x4*>(out + i4 * 4) = o;
}

extern "C" void kernel_launch(void* const* d_in, const int* in_sizes, int n_in,
                              void* d_out, int out_size, void* d_ws, size_t ws_size,
                              hipStream_t stream) {
  const float* feats = (const float*)d_in[0];
  const int* in_idx  = (const int*)d_in[1];
  const int* out_idx = (const int*)d_in[2];
  const float* W1  = (const float*)d_in[3];
  const float* g1  = (const float*)d_in[4];
  const float* b1  = (const float*)d_in[5];
  const float* W2  = (const float*)d_in[6];
  const float* g2  = (const float*)d_in[7];
  const float* b2  = (const float*)d_in[8];
  const float* Wsc = (const float*)d_in[9];
  const float* gsc = (const float*)d_in[10];
  const float* bsc = (const float*)d_in[11];

  char* ws = (char*)d_ws;
  size_t off = 0;
  auto alloc = [&](size_t bytes) {
    void* p = ws + off; off += (bytes + 255) & ~(size_t)255; return p;
  };
  float* stats = (float*)alloc(768 * 4);               // [s1,q1,ssc,qsc,s2,q2] x128
  float* rtmp  = (float*)alloc(32 * 512 * 4);          // reduce stage-1 output
  u16* Xbf  = (u16*)alloc((size_t)(NS + 1) * 64 * 2);
  u16* SCbf = (u16*)alloc((size_t)NS * 128 * 2);
  u16* Hbf  = (u16*)alloc((size_t)(NS + 1) * 128 * 2);
  u16* Y2bf = (u16*)alloc((size_t)NS * 128 * 2);
  u16* Wp1  = (u16*)alloc((size_t)NK * 64 * 128 * 2);
  u16* Wp2  = (u16*)alloc((size_t)NK * 128 * 128 * 2);
  u16* Wpsc = (u16*)alloc((size_t)64 * 128 * 2);
  // d_out (102.4MB) hosts y1 bf16 (51.2MB) + fused gidx (21.6MB); k_final overwrites
  u16* Y1bf = (u16*)d_out;
  int* gidx = (int*)((char*)d_out + (size_t)NS * 128 * 2);
  float* part1 = (float*)Y2bf;          // dead region until conv2
  float* part2 = (float*)Xbf;           // Xbf dead after conv1

  hipLaunchKernelGGL(k_prep_x, dim3(50001), dim3(256), 0, stream, feats, Xbf, stats);
  hipLaunchKernelGGL(k_prep_gidx, dim3((NK * NS + 255) / 256), dim3(256), 0, stream,
                     in_idx, out_idx, gidx);
  hipLaunchKernelGGL(k_pack_w, dim3(2624), dim3(256), 0, stream, W1, W2, Wsc, Wp1, Wp2, Wpsc);
  hipLaunchKernelGGL((k_conv<64, true>), dim3(NBLK), dim3(512), 0, stream,
                     Xbf, Wp1, Wpsc, gidx, Y1bf, SCbf, part1);
  hipLaunchKernelGGL(k_red1, dim3(2, 32), dim3(256), 0, stream, part1, rtmp, 512, NBLK);
  hipLaunchKernelGGL(k_red2, dim3(2), dim3(256), 0, stream, rtmp, stats, 512);
  hipLaunchKernelGGL(k_bnrelu, dim3(12501), dim3(256), 0, stream, Y1bf, stats, g1, b1, Hbf);
  hipLaunchKernelGGL((k_conv<128, false>), dim3(NBLK), dim3(512), 0, stream,
                     Hbf, Wp2, nullptr, gidx, Y2bf, nullptr, part2);
  hipLaunchKernelGGL(k_red1, dim3(1, 32), dim3(256), 0, stream, part2, rtmp, 256, NBLK);
  hipLaunchKernelGGL(k_red2, dim3(1), dim3(256), 0, stream, rtmp, stats + 512, 256);
  hipLaunchKernelGGL(k_final, dim3(25000), dim3(256), 0, stream,
                     Y2bf, SCbf, stats, g2, b2, gsc, bsc, (float*)d_out);
}

// Round 6
// 615.547 us; speedup vs baseline: 1.1490x; 1.1490x over previous
//
#include <hip/hip_runtime.h>

#define NS 200000
#define NK 27
#define NB 1563   // ceil(NS/128)
#define EPSV 1e-5f

typedef __bf16 bf16x8 __attribute__((ext_vector_type(8)));
typedef float f32x4 __attribute__((ext_vector_type(4)));
typedef unsigned short u16;
typedef u16 u16x8 __attribute__((ext_vector_type(8)));
typedef u16 u16x4 __attribute__((ext_vector_type(4)));
typedef unsigned u32;

__device__ __forceinline__ u16 f2bf(float f) {
  union { float f; unsigned u; } v; v.f = f;
  unsigned r = v.u + 0x7fffu + ((v.u >> 16) & 1u);
  return (u16)(r >> 16);
}
__device__ __forceinline__ float bf2f(u16 u) {
  union { unsigned u; float f; } v; v.u = ((unsigned)u) << 16;
  return v.f;
}

// ---- prep: zero stats, feats f32 -> bf16 with zero row at N ----
__global__ void k_prep_x(const float* __restrict__ feats, u16* __restrict__ Xbf,
                         float* __restrict__ stats) {
  long i = (long)blockIdx.x * 256 + threadIdx.x;
  if (i < 768) stats[i] = 0.f;
  const long total = (long)(NS + 1) * 64;
  if (i < total) {
    long row = i >> 6;
    Xbf[i] = (row < NS) ? f2bf(feats[i]) : (u16)0;
  }
}

// ---- fused gather index: gidx = valid ? in_idx : NS ----
__global__ void k_prep_gidx(const int* __restrict__ in_idx, const int* __restrict__ out_idx,
                            int* __restrict__ gidx) {
  long i = (long)blockIdx.x * 256 + threadIdx.x;
  if (i < (long)NK * NS) gidx[i] = (out_idx[i] != NS) ? in_idx[i] : NS;
}

// ---- pack W [K][C][128] f32 -> lane-linear MFMA-B-fragment bf16 ----
// packed f = ((k*S+s)*8+cf)*512 + l*8 + j  <->  W[k][s*32+(l>>4)*8+j][cf*16+(l&15)]
// Lane l reads bytes [l*16, l*16+16) of each 1024B fragment block:
// ds_read_b128 is conflict-free and global reads are perfectly coalesced.
__global__ void k_pack_w(const float* __restrict__ W1, const float* __restrict__ W2,
                         const float* __restrict__ Wsc, u16* __restrict__ Wp1,
                         u16* __restrict__ Wp2, u16* __restrict__ Wpsc) {
  int i = blockIdx.x * 256 + threadIdx.x;
  const int n1 = NK * 64 * 128, n2 = NK * 128 * 128, n3 = 64 * 128;
  const float* src; u16* dst; int f, S, C;
  if (i < n1)            { src = W1;  dst = Wp1;  f = i;            S = 2; C = 64; }
  else if (i < n1 + n2)  { src = W2;  dst = Wp2;  f = i - n1;       S = 4; C = 128; }
  else if (i < n1 + n2 + n3) { src = Wsc; dst = Wpsc; f = i - n1 - n2; S = 2; C = 64; }
  else return;
  int j = f & 7, l = (f >> 3) & 63, cf = (f >> 9) & 7;
  int rest = f >> 12;
  int s = rest % S, k = rest / S;
  int kk = s * 32 + (l >> 4) * 8 + j;
  dst[f] = f2bf(src[(k * C + kk) * 128 + cf * 16 + (l & 15)]);
}

// ---- gather-GEMM conv: 4 waves (2m x 2n), wave tile 64 rows x 64 cols.
// W staged in LDS (dbuf, global_load_lds, lane-linear pack); A gathered
// per-lane into registers with half-K rotating buffers; exact counted-vmcnt
// barriers (T3/T4); setprio around MFMA clusters (T5). ----
template <int C, bool FUSE_SC>
__global__ __launch_bounds__(256, 2) void k_conv(
    const u16* __restrict__ X, const u16* __restrict__ Wp, const u16* __restrict__ Wpsc,
    const int* __restrict__ gidx,
    u16* __restrict__ Y, u16* __restrict__ SCb, float* __restrict__ partial) {
  constexpr int S = C / 32;            // K-slices of 32 (4 or 2)
  constexpr int SH = S / 2;            // slices per half (2 or 1)
  constexpr int SLICE = C * 128;       // u16 elems per packed k-slice
  constexpr int NST = C / 16;          // global_load_lds per wave per k (8 / 4)
  constexpr int NG = 4 * SH;           // gather loads per wave per half (8 / 4)
  constexpr int WAITA = NG + 4 + NST;  // G1(k) + I(k+1) + S(k+1)  (20 / 12)
  constexpr int PC = FUSE_SC ? 512 : 256;
  __shared__ alignas(16) u16 Wbuf[2 * SLICE];
  float* red = reinterpret_cast<float*>(Wbuf);  // 512 f32 overlay (sync-guarded)

  const int t = threadIdx.x, w = t >> 6, l = t & 63;
  const int lr = l & 15, lh = l >> 4;
  const int wm = w >> 1, wn = w & 1;
  const int rowbase = blockIdx.x * 128 + wm * 64;
  const int laneoff = l * 8;

  int rr[4]; bool ok[4]; long rc[4]; int sv[4];
  #pragma unroll
  for (int m = 0; m < 4; ++m) {
    rr[m] = rowbase + m * 16 + lr;
    ok[m] = rr[m] < NS;
    rc[m] = ok[m] ? rr[m] : 0;
  }

  auto stage = [&](int k, int p) {
    #pragma unroll
    for (int i = 0; i < NST; ++i) {
      const u16* g = Wp + (long)k * SLICE + (w * NST + i) * 512 + l * 8;
      u16* d = &Wbuf[p * SLICE + (w * NST + i) * 512];
      __builtin_amdgcn_global_load_lds(
          (const __attribute__((address_space(1))) u32*)g,
          (__attribute__((address_space(3))) u32*)d, 16, 0, 0);
    }
  };
  auto loadidx = [&](int k) {
    #pragma unroll
    for (int m = 0; m < 4; ++m) {
      int v = gidx[(long)k * NS + rc[m]];
      sv[m] = ok[m] ? v : NS;
    }
  };
  auto gather = [&](int h, bf16x8 (&a)[4][SH]) {
    #pragma unroll
    for (int m = 0; m < 4; ++m) {
      const u16* rowp = X + (long)sv[m] * C + lh * 8;
      #pragma unroll
      for (int si = 0; si < SH; ++si)
        a[m][si] = *reinterpret_cast<const bf16x8*>(rowp + (h * SH + si) * 32);
    }
  };
  auto compute = [&](int p, int h, const bf16x8 (&a)[4][SH], f32x4 (&ac)[4][4]) {
    __builtin_amdgcn_s_setprio(1);
    #pragma unroll
    for (int si = 0; si < SH; ++si) {
      int s = h * SH + si;
      #pragma unroll
      for (int nf = 0; nf < 4; ++nf) {
        bf16x8 b = *reinterpret_cast<const bf16x8*>(
            &Wbuf[p * SLICE + (s * 8 + wn * 4 + nf) * 512 + laneoff]);
        #pragma unroll
        for (int m = 0; m < 4; ++m)
          ac[m][nf] = __builtin_amdgcn_mfma_f32_16x16x32_bf16(a[m][si], b, ac[m][nf], 0, 0, 0);
      }
    }
    __builtin_amdgcn_s_setprio(0);
  };
  auto emit = [&](f32x4 (&ac)[4][4], u16* __restrict__ Yp, int poff) {
    #pragma unroll
    for (int m = 0; m < 4; ++m)
      #pragma unroll
      for (int nf = 0; nf < 4; ++nf) {
        int ch = wn * 64 + nf * 16 + lr;
        #pragma unroll
        for (int r = 0; r < 4; ++r) {
          long row = rowbase + m * 16 + lh * 4 + r;
          if (row < NS) Yp[row * 128 + ch] = f2bf(ac[m][nf][r]);
        }
      }
    __syncthreads();  // all LDS W-reads done; red overlay is safe
    #pragma unroll
    for (int nf = 0; nf < 4; ++nf) {
      float s = 0.f, q = 0.f;
      #pragma unroll
      for (int m = 0; m < 4; ++m)
        #pragma unroll
        for (int r = 0; r < 4; ++r) { float v = ac[m][nf][r]; s += v; q += v * v; }
      s += __shfl_xor(s, 16); s += __shfl_xor(s, 32);
      q += __shfl_xor(q, 16); q += __shfl_xor(q, 32);
      if (lh == 0) {
        red[w * 128 + nf * 16 + lr] = s;
        red[w * 128 + 64 + nf * 16 + lr] = q;
      }
    }
    __syncthreads();
    if (t < 256) {
      int stat = t >> 7, c = t & 127, wnc = c >> 6, lc = c & 63;
      partial[(long)blockIdx.x * PC + poff + t] =
          red[wnc * 128 + stat * 64 + lc] + red[(2 + wnc) * 128 + stat * 64 + lc];
    }
    __syncthreads();
  };

  if constexpr (FUSE_SC) {
    // shortcut: identity gather of own rows, B-frags direct from global (one-time)
    bf16x8 ai[4][2];
    #pragma unroll
    for (int m = 0; m < 4; ++m) {
      long srcr = ok[m] ? rr[m] : NS;
      #pragma unroll
      for (int s = 0; s < 2; ++s)
        ai[m][s] = *reinterpret_cast<const bf16x8*>(X + srcr * 64 + (s * 4 + lh) * 8);
    }
    f32x4 asc[4][4];
    #pragma unroll
    for (int m = 0; m < 4; ++m)
      #pragma unroll
      for (int nf = 0; nf < 4; ++nf) asc[m][nf] = (f32x4){0.f, 0.f, 0.f, 0.f};
    #pragma unroll
    for (int s = 0; s < 2; ++s)
      #pragma unroll
      for (int nf = 0; nf < 4; ++nf) {
        bf16x8 b = *reinterpret_cast<const bf16x8*>(
            Wpsc + (s * 8 + wn * 4 + nf) * 512 + laneoff);
        #pragma unroll
        for (int m = 0; m < 4; ++m)
          asc[m][nf] = __builtin_amdgcn_mfma_f32_16x16x32_bf16(ai[m][s], b, asc[m][nf], 0, 0, 0);
      }
    emit(asc, SCb, 256);  // ends fully drained
  }

  f32x4 acc[4][4];
  #pragma unroll
  for (int m = 0; m < 4; ++m)
    #pragma unroll
    for (int nf = 0; nf < 4; ++nf) acc[m][nf] = (f32x4){0.f, 0.f, 0.f, 0.f};

  bf16x8 avA[4][SH], avB[4][SH];

  // ---- prologue: idx(0), W-stage(0), both gather halves of k=0 ----
  loadidx(0);
  stage(0, 0);
  gather(0, avA);
  gather(1, avB);

  // ---- main loop (k = 0..25), exact counted waits ----
  #pragma unroll 1
  for (int k = 0; k < NK - 1; ++k) {
    const int p = k & 1;
    loadidx(k + 1);          // 4 idx loads (issued first so their wait keeps S in flight)
    stage(k + 1, p ^ 1);     // NST global_load_lds
    asm volatile("s_waitcnt vmcnt(%0)\n\ts_barrier" :: "i"(WAITA) : "memory");
    compute(p, 0, avA, acc);
    gather(0, avA);          // k+1 half0 (WAR-safe: avA reads done)
    compute(p, 1, avB, acc);
    gather(1, avB);          // k+1 half1
    asm volatile("s_waitcnt lgkmcnt(0)\n\ts_barrier" ::: "memory");
  }
  // ---- tail k = 26 (parity 0; staged in iter 25) ----
  asm volatile("s_waitcnt vmcnt(%0)\n\ts_barrier" :: "i"(NG) : "memory");
  compute(0, 0, avA, acc);
  asm volatile("s_waitcnt vmcnt(0)" ::: "memory");
  compute(0, 1, avB, acc);

  emit(acc, Y, 0);
}

// ---- deterministic 2-stage partial reduce ----
__global__ void k_red1(const float* __restrict__ part, float* __restrict__ tmp,
                       int pc, int nrows) {
  int c = blockIdx.x * 256 + threadIdx.x;
  float s = 0.f;
  for (int r = blockIdx.y; r < nrows; r += 32) s += part[(long)r * pc + c];
  tmp[(long)blockIdx.y * pc + c] = s;
}
__global__ void k_red2(const float* __restrict__ tmp, float* __restrict__ out, int pc) {
  int c = blockIdx.x * 256 + threadIdx.x;
  float s = 0.f;
  #pragma unroll
  for (int r = 0; r < 32; ++r) s += tmp[(long)r * pc + c];
  out[c] = s;
}

// ---- h = relu(bn1(y1)) -> bf16 (+ zero dummy row N) ----
__global__ void k_bnrelu(const u16* __restrict__ Y1, const float* __restrict__ stats,
                         const float* __restrict__ g, const float* __restrict__ b,
                         u16* __restrict__ H) {
  long i8 = (long)blockIdx.x * 256 + threadIdx.x;
  const long tot = (long)(NS + 1) * 16;
  if (i8 >= tot) return;
  long row = i8 >> 4;
  u16x8 o;
  if (row < NS) {
    int ch0 = ((int)i8 & 15) * 8;
    u16x8 y = *reinterpret_cast<const u16x8*>(Y1 + i8 * 8);
    #pragma unroll
    for (int e = 0; e < 8; ++e) {
      int ch = ch0 + e;
      float m = stats[ch] * (1.f / NS);
      float var = stats[128 + ch] * (1.f / NS) - m * m;
      float a = g[ch] * rsqrtf(var + EPSV);
      float bb = b[ch] - m * a;
      float h = bf2f(y[e]) * a + bb;
      o[e] = f2bf(h > 0.f ? h : 0.f);
    }
  } else {
    #pragma unroll
    for (int e = 0; e < 8; ++e) o[e] = (u16)0;
  }
  *reinterpret_cast<u16x8*>(H + i8 * 8) = o;
}

// ---- out = relu(bn2(y2) + bnsc(sc)) f32 ----
__global__ void k_final(const u16* __restrict__ Y2, const u16* __restrict__ SCb,
                        const float* __restrict__ stats,
                        const float* __restrict__ g2, const float* __restrict__ b2,
                        const float* __restrict__ gsc, const float* __restrict__ bsc,
                        float* __restrict__ out) {
  long i4 = (long)blockIdx.x * 256 + threadIdx.x;
  if (i4 >= (long)NS * 32) return;
  int ch0 = ((int)i4 & 31) * 4;
  u16x4 y = *reinterpret_cast<const u16x4*>(Y2 + i4 * 4);
  u16x4 s = *reinterpret_cast<const u16x4*>(SCb + i4 * 4);
  f32x4 o;
  #pragma unroll
  for (int e = 0; e < 4; ++e) {
    int ch = ch0 + e;
    float m2 = stats[512 + ch] * (1.f / NS);
    float v2 = stats[640 + ch] * (1.f / NS) - m2 * m2;
    float a2 = g2[ch] * rsqrtf(v2 + EPSV);
    float msc = stats[256 + ch] * (1.f / NS);
    float vsc = stats[384 + ch] * (1.f / NS) - msc * msc;
    float asc = gsc[ch] * rsqrtf(vsc + EPSV);
    float val = bf2f(y[e]) * a2 + (b2[ch] - m2 * a2)
              + bf2f(s[e]) * asc + (bsc[ch] - msc * asc);
    o[e] = val > 0.f ? val : 0.f;
  }
  *reinterpret_cast<f32x4*>(out + i4 * 4) = o;
}

extern "C" void kernel_launch(void* const* d_in, const int* in_sizes, int n_in,
                              void* d_out, int out_size, void* d_ws, size_t ws_size,
                              hipStream_t stream) {
  const float* feats = (const float*)d_in[0];
  const int* in_idx  = (const int*)d_in[1];
  const int* out_idx = (const int*)d_in[2];
  const float* W1  = (const float*)d_in[3];
  const float* g1  = (const float*)d_in[4];
  const float* b1  = (const float*)d_in[5];
  const float* W2  = (const float*)d_in[6];
  const float* g2  = (const float*)d_in[7];
  const float* b2  = (const float*)d_in[8];
  const float* Wsc = (const float*)d_in[9];
  const float* gsc = (const float*)d_in[10];
  const float* bsc = (const float*)d_in[11];

  char* ws = (char*)d_ws;
  size_t off = 0;
  auto alloc = [&](size_t bytes) {
    void* p = ws + off; off += (bytes + 255) & ~(size_t)255; return p;
  };
  float* stats = (float*)alloc(768 * 4);               // [s1,q1,ssc,qsc,s2,q2] x128
  float* rtmp  = (float*)alloc(32 * 512 * 4);          // reduce stage-1 output
  u16* Xbf  = (u16*)alloc((size_t)(NS + 1) * 64 * 2);
  u16* SCbf = (u16*)alloc((size_t)NS * 128 * 2);
  u16* Hbf  = (u16*)alloc((size_t)(NS + 1) * 128 * 2);
  u16* Y2bf = (u16*)alloc((size_t)NS * 128 * 2);
  u16* Wp1  = (u16*)alloc((size_t)NK * 64 * 128 * 2);
  u16* Wp2  = (u16*)alloc((size_t)NK * 128 * 128 * 2);
  u16* Wpsc = (u16*)alloc((size_t)64 * 128 * 2);
  // d_out (102.4MB) hosts y1 bf16 (51.2MB) + fused gidx (21.6MB); k_final overwrites
  u16* Y1bf = (u16*)d_out;
  int* gidx = (int*)((char*)d_out + (size_t)NS * 128 * 2);
  float* part1 = (float*)Y2bf;          // dead region until conv2
  float* part2 = (float*)Xbf;           // Xbf dead after conv1

  hipLaunchKernelGGL(k_prep_x, dim3(50001), dim3(256), 0, stream, feats, Xbf, stats);
  hipLaunchKernelGGL(k_prep_gidx, dim3((NK * NS + 255) / 256), dim3(256), 0, stream,
                     in_idx, out_idx, gidx);
  hipLaunchKernelGGL(k_pack_w, dim3(2624), dim3(256), 0, stream, W1, W2, Wsc, Wp1, Wp2, Wpsc);
  hipLaunchKernelGGL((k_conv<64, true>), dim3(NB), dim3(256), 0, stream,
                     Xbf, Wp1, Wpsc, gidx, Y1bf, SCbf, part1);
  hipLaunchKernelGGL(k_red1, dim3(2, 32), dim3(256), 0, stream, part1, rtmp, 512, NB);
  hipLaunchKernelGGL(k_red2, dim3(2), dim3(256), 0, stream, rtmp, stats, 512);
  hipLaunchKernelGGL(k_bnrelu, dim3(12501), dim3(256), 0, stream, Y1bf, stats, g1, b1, Hbf);
  hipLaunchKernelGGL((k_conv<128, false>), dim3(NB), dim3(256), 0, stream,
                     Hbf, Wp2, nullptr, gidx, Y2bf, nullptr, part2);
  hipLaunchKernelGGL(k_red1, dim3(1, 32), dim3(256), 0, stream, part2, rtmp, 256, NB);
  hipLaunchKernelGGL(k_red2, dim3(1), dim3(256), 0, stream, rtmp, stats + 512, 256);
  hipLaunchKernelGGL(k_final, dim3(25000), dim3(256), 0, stream,
                     Y2bf, SCbf, stats, g2, b2, gsc, bsc, (float*)d_out);
}

// Round 7
// 497.120 us; speedup vs baseline: 1.4228x; 1.2382x over previous
//
#include <hip/hip_runtime.h>

#define NS 200000
#define NK 27
#define NB 1563   // ceil(NS/128)
#define EPSV 1e-5f

typedef __bf16 bf16x8 __attribute__((ext_vector_type(8)));
typedef float f32x4 __attribute__((ext_vector_type(4)));
typedef unsigned short u16;
typedef u16 u16x8 __attribute__((ext_vector_type(8)));
typedef u16 u16x4 __attribute__((ext_vector_type(4)));
typedef unsigned u32;

__device__ __forceinline__ u16 f2bf(float f) {
  union { float f; unsigned u; } v; v.f = f;
  unsigned r = v.u + 0x7fffu + ((v.u >> 16) & 1u);
  return (u16)(r >> 16);
}
__device__ __forceinline__ float bf2f(u16 u) {
  union { unsigned u; float f; } v; v.u = ((unsigned)u) << 16;
  return v.f;
}

// ---- prep: zero stats, feats f32 -> bf16 ----
__global__ void k_prep_x(const float* __restrict__ feats, u16* __restrict__ Xbf,
                         float* __restrict__ stats) {
  long i = (long)blockIdx.x * 256 + threadIdx.x;
  if (i < 768) stats[i] = 0.f;
  const long total = (long)NS * 64;
  if (i < total) Xbf[i] = f2bf(feats[i]);
}

// ---- fused gather index: gidx = valid ? in_idx : NS ----
__global__ void k_prep_gidx(const int* __restrict__ in_idx, const int* __restrict__ out_idx,
                            int* __restrict__ gidx) {
  long i = (long)blockIdx.x * 256 + threadIdx.x;
  if (i < (long)NK * NS) gidx[i] = (out_idx[i] != NS) ? in_idx[i] : NS;
}

// ---- pack W [K][C][128] f32 -> lane-linear MFMA-B-fragment bf16 ----
// packed f = ((k*S+s)*8+cf)*512 + l*8 + j  <->  W[k][s*32+(l>>4)*8+j][cf*16+(l&15)]
__global__ void k_pack_w(const float* __restrict__ W1, const float* __restrict__ W2,
                         const float* __restrict__ Wsc, u16* __restrict__ Wp1,
                         u16* __restrict__ Wp2, u16* __restrict__ Wpsc) {
  int i = blockIdx.x * 256 + threadIdx.x;
  const int n1 = NK * 64 * 128, n2 = NK * 128 * 128, n3 = 64 * 128;
  const float* src; u16* dst; int f, S, C;
  if (i < n1)            { src = W1;  dst = Wp1;  f = i;            S = 2; C = 64; }
  else if (i < n1 + n2)  { src = W2;  dst = Wp2;  f = i - n1;       S = 4; C = 128; }
  else if (i < n1 + n2 + n3) { src = Wsc; dst = Wpsc; f = i - n1 - n2; S = 2; C = 64; }
  else return;
  int j = f & 7, l = (f >> 3) & 63, cf = (f >> 9) & 7;
  int rest = f >> 12;
  int s = rest % S, k = rest / S;
  int kk = s * 32 + (l >> 4) * 8 + j;
  dst[f] = f2bf(src[(k * C + kk) * 128 + cf * 16 + (l & 15)]);
}

// ---- gather-GEMM conv: 4 waves x 32 rows (dup-free), wave tile 32x128.
// W in LDS (dbuf via global_load_lds, lane-linear); A gathered per-lane,
// CONDITIONAL (invalid pairs skip the load entirely - 59% fewer L1 probes);
// gathers issued after the counted-vmcnt barrier so the static vmcnt only
// counts the 12 unconditional stage+idx ops. ----
template <int C, bool FUSE_SC>
__global__ __launch_bounds__(256, (C == 64) ? 3 : 2) void k_conv(
    const u16* __restrict__ X, const u16* __restrict__ Wp, const u16* __restrict__ Wpsc,
    const int* __restrict__ gidx,
    u16* __restrict__ Y, u16* __restrict__ SCb, float* __restrict__ partial) {
  constexpr int S = C / 32;            // K-slices of 32 (4 or 2)
  constexpr int SLICE = C * 128;       // u16 elems per packed k-slice
  constexpr int NST = C / 16;          // global_load_lds per wave per k (8 / 4)
  constexpr int WAITN = NST + 4;       // newest unconditional ops kept in flight
  constexpr int PC = FUSE_SC ? 512 : 256;
  __shared__ alignas(16) u16 Wbuf[2 * SLICE];
  float* red = reinterpret_cast<float*>(Wbuf);  // 4KB overlay (sync-guarded)

  const int t = threadIdx.x, w = t >> 6, l = t & 63;
  const int lr = l & 15, lh = l >> 4;
  const int rowbase = blockIdx.x * 128 + w * 32;
  const int laneoff = l * 8;

  int rr[2]; bool ok[2]; long rc[2];
  #pragma unroll
  for (int m = 0; m < 2; ++m) {
    rr[m] = rowbase + m * 16 + lr;
    ok[m] = rr[m] < NS;
    rc[m] = ok[m] ? rr[m] : 0;
  }

  auto stage = [&](int k, int p) {
    #pragma unroll
    for (int i = 0; i < NST; ++i) {
      const u16* g = Wp + (long)k * SLICE + (w * NST + i) * 512 + l * 8;
      u16* d = &Wbuf[p * SLICE + (w * NST + i) * 512];
      __builtin_amdgcn_global_load_lds(
          (const __attribute__((address_space(1))) u32*)g,
          (__attribute__((address_space(3))) u32*)d, 16, 0, 0);
    }
  };
  auto loadidx = [&](int k, int (&dst)[2]) {
    #pragma unroll
    for (int m = 0; m < 2; ++m) {
      int v = gidx[(long)k * NS + rc[m]];
      dst[m] = ok[m] ? v : NS;
    }
  };
  // conditional gather: invalid rows produce zeros without touching memory
  auto gather = [&](const int (&src)[2], bf16x8 (&a)[2][S]) {
    #pragma unroll
    for (int m = 0; m < 2; ++m) {
      #pragma unroll
      for (int s = 0; s < S; ++s) a[m][s] = bf16x8{};
      if (src[m] != NS) {
        const u16* rowp = X + (long)src[m] * C + lh * 8;
        #pragma unroll
        for (int s = 0; s < S; ++s)
          a[m][s] = *reinterpret_cast<const bf16x8*>(rowp + s * 32);
      }
    }
  };
  auto compute = [&](int p, const bf16x8 (&a)[2][S], f32x4 (&ac)[2][8]) {
    __builtin_amdgcn_s_setprio(1);
    #pragma unroll
    for (int s = 0; s < S; ++s)
      #pragma unroll
      for (int cf = 0; cf < 8; ++cf) {
        bf16x8 b = *reinterpret_cast<const bf16x8*>(
            &Wbuf[p * SLICE + (s * 8 + cf) * 512 + laneoff]);
        ac[0][cf] = __builtin_amdgcn_mfma_f32_16x16x32_bf16(a[0][s], b, ac[0][cf], 0, 0, 0);
        ac[1][cf] = __builtin_amdgcn_mfma_f32_16x16x32_bf16(a[1][s], b, ac[1][cf], 0, 0, 0);
      }
    __builtin_amdgcn_s_setprio(0);
  };
  auto emit = [&](f32x4 (&ac)[2][8], u16* __restrict__ Yp, int poff) {
    #pragma unroll
    for (int m = 0; m < 2; ++m)
      #pragma unroll
      for (int cf = 0; cf < 8; ++cf) {
        int ch = cf * 16 + lr;
        #pragma unroll
        for (int r = 0; r < 4; ++r) {
          long row = rowbase + m * 16 + lh * 4 + r;
          if (row < NS) Yp[row * 128 + ch] = f2bf(ac[m][cf][r]);
        }
      }
    __syncthreads();  // full drain; red overlay safe
    #pragma unroll
    for (int cf = 0; cf < 8; ++cf) {
      float s = 0.f, q = 0.f;
      #pragma unroll
      for (int m = 0; m < 2; ++m)
        #pragma unroll
        for (int r = 0; r < 4; ++r) { float v = ac[m][cf][r]; s += v; q += v * v; }
      s += __shfl_xor(s, 16); s += __shfl_xor(s, 32);
      q += __shfl_xor(q, 16); q += __shfl_xor(q, 32);
      if (lh == 0) {
        red[w * 256 + cf * 16 + lr] = s;
        red[w * 256 + 128 + cf * 16 + lr] = q;
      }
    }
    __syncthreads();
    if (t < 256)
      partial[(long)blockIdx.x * PC + poff + t] =
          red[t] + red[256 + t] + red[512 + t] + red[768 + t];
    __syncthreads();
  };

  if constexpr (FUSE_SC) {
    // shortcut: identity "gather" of own rows, B-frags direct from global
    bf16x8 ai[2][2];
    #pragma unroll
    for (int m = 0; m < 2; ++m) {
      #pragma unroll
      for (int s = 0; s < 2; ++s) ai[m][s] = bf16x8{};
      if (ok[m]) {
        #pragma unroll
        for (int s = 0; s < 2; ++s)
          ai[m][s] = *reinterpret_cast<const bf16x8*>(X + (long)rr[m] * 64 + lh * 8 + s * 32);
      }
    }
    f32x4 asc[2][8];
    #pragma unroll
    for (int m = 0; m < 2; ++m)
      #pragma unroll
      for (int cf = 0; cf < 8; ++cf) asc[m][cf] = (f32x4){0.f, 0.f, 0.f, 0.f};
    #pragma unroll
    for (int s = 0; s < 2; ++s)
      #pragma unroll
      for (int cf = 0; cf < 8; ++cf) {
        bf16x8 b = *reinterpret_cast<const bf16x8*>(Wpsc + (s * 8 + cf) * 512 + laneoff);
        asc[0][cf] = __builtin_amdgcn_mfma_f32_16x16x32_bf16(ai[0][s], b, asc[0][cf], 0, 0, 0);
        asc[1][cf] = __builtin_amdgcn_mfma_f32_16x16x32_bf16(ai[1][s], b, asc[1][cf], 0, 0, 0);
      }
    emit(asc, SCb, 256);  // ends fully drained (syncthreads)
  }

  f32x4 acc[2][8];
  #pragma unroll
  for (int m = 0; m < 2; ++m)
    #pragma unroll
    for (int cf = 0; cf < 8; ++cf) acc[m][cf] = (f32x4){0.f, 0.f, 0.f, 0.f};

  int sv0[2], sv1[2];
  bf16x8 av0[2][S], av1[2][S];

  // ---- prologue: I(0), S(0), G(0), I(1) ----
  loadidx(0, sv0);
  stage(0, 0);
  gather(sv0, av0);
  loadidx(1, sv1);

  // ---- main loop, two k per iteration (static parity) ----
  #pragma unroll 1
  for (int k = 0; k < NK - 1; k += 2) {
    // step A: compute k (buf 0, av0)
    stage(k + 1, 1);
    loadidx(k + 2, sv0);
    asm volatile("s_waitcnt vmcnt(%0)\n\ts_barrier" :: "i"(WAITN) : "memory");
    gather(sv1, av1);            // G(k+1): rides across compute(k)
    compute(0, av0, acc);
    asm volatile("s_waitcnt lgkmcnt(0)\n\ts_barrier" ::: "memory");
    // step B: compute k+1 (buf 1, av1)
    stage(k + 2, 0);             // k+2 <= 26 always here
    { int kn = k + 3 < NK ? k + 3 : NK - 1; loadidx(kn, sv1); }
    asm volatile("s_waitcnt vmcnt(%0)\n\ts_barrier" :: "i"(WAITN) : "memory");
    gather(sv0, av0);            // G(k+2)
    compute(1, av1, acc);
    asm volatile("s_waitcnt lgkmcnt(0)\n\ts_barrier" ::: "memory");
  }
  // ---- tail k = 26 (buf 0 staged at k=24 step B, av0 gathered there) ----
  asm volatile("s_waitcnt vmcnt(0)\n\ts_barrier" ::: "memory");
  compute(0, av0, acc);

  emit(acc, Y, 0);
}

// ---- deterministic 2-stage partial reduce ----
__global__ void k_red1(const float* __restrict__ part, float* __restrict__ tmp,
                       int pc, int nrows) {
  int c = blockIdx.x * 256 + threadIdx.x;
  float s = 0.f;
  for (int r = blockIdx.y; r < nrows; r += 32) s += part[(long)r * pc + c];
  tmp[(long)blockIdx.y * pc + c] = s;
}
__global__ void k_red2(const float* __restrict__ tmp, float* __restrict__ out, int pc) {
  int c = blockIdx.x * 256 + threadIdx.x;
  float s = 0.f;
  #pragma unroll
  for (int r = 0; r < 32; ++r) s += tmp[(long)r * pc + c];
  out[c] = s;
}

// ---- h = relu(bn1(y1)) -> bf16 ----
__global__ void k_bnrelu(const u16* __restrict__ Y1, const float* __restrict__ stats,
                         const float* __restrict__ g, const float* __restrict__ b,
                         u16* __restrict__ H) {
  long i8 = (long)blockIdx.x * 256 + threadIdx.x;
  const long tot = (long)NS * 16;
  if (i8 >= tot) return;
  int ch0 = ((int)i8 & 15) * 8;
  u16x8 y = *reinterpret_cast<const u16x8*>(Y1 + i8 * 8);
  u16x8 o;
  #pragma unroll
  for (int e = 0; e < 8; ++e) {
    int ch = ch0 + e;
    float m = stats[ch] * (1.f / NS);
    float var = stats[128 + ch] * (1.f / NS) - m * m;
    float a = g[ch] * rsqrtf(var + EPSV);
    float bb = b[ch] - m * a;
    float h = bf2f(y[e]) * a + bb;
    o[e] = f2bf(h > 0.f ? h : 0.f);
  }
  *reinterpret_cast<u16x8*>(H + i8 * 8) = o;
}

// ---- out = relu(bn2(y2) + bnsc(sc)) f32 ----
__global__ void k_final(const u16* __restrict__ Y2, const u16* __restrict__ SCb,
                        const float* __restrict__ stats,
                        const float* __restrict__ g2, const float* __restrict__ b2,
                        const float* __restrict__ gsc, const float* __restrict__ bsc,
                        float* __restrict__ out) {
  long i4 = (long)blockIdx.x * 256 + threadIdx.x;
  if (i4 >= (long)NS * 32) return;
  int ch0 = ((int)i4 & 31) * 4;
  u16x4 y = *reinterpret_cast<const u16x4*>(Y2 + i4 * 4);
  u16x4 s = *reinterpret_cast<const u16x4*>(SCb + i4 * 4);
  f32x4 o;
  #pragma unroll
  for (int e = 0; e < 4; ++e) {
    int ch = ch0 + e;
    float m2 = stats[512 + ch] * (1.f / NS);
    float v2 = stats[640 + ch] * (1.f / NS) - m2 * m2;
    float a2 = g2[ch] * rsqrtf(v2 + EPSV);
    float msc = stats[256 + ch] * (1.f / NS);
    float vsc = stats[384 + ch] * (1.f / NS) - msc * msc;
    float asc = gsc[ch] * rsqrtf(vsc + EPSV);
    float val = bf2f(y[e]) * a2 + (b2[ch] - m2 * a2)
              + bf2f(s[e]) * asc + (bsc[ch] - msc * asc);
    o[e] = val > 0.f ? val : 0.f;
  }
  *reinterpret_cast<f32x4*>(out + i4 * 4) = o;
}

extern "C" void kernel_launch(void* const* d_in, const int* in_sizes, int n_in,
                              void* d_out, int out_size, void* d_ws, size_t ws_size,
                              hipStream_t stream) {
  const float* feats = (const float*)d_in[0];
  const int* in_idx  = (const int*)d_in[1];
  const int* out_idx = (const int*)d_in[2];
  const float* W1  = (const float*)d_in[3];
  const float* g1  = (const float*)d_in[4];
  const float* b1  = (const float*)d_in[5];
  const float* W2  = (const float*)d_in[6];
  const float* g2  = (const float*)d_in[7];
  const float* b2  = (const float*)d_in[8];
  const float* Wsc = (const float*)d_in[9];
  const float* gsc = (const float*)d_in[10];
  const float* bsc = (const float*)d_in[11];

  char* ws = (char*)d_ws;
  size_t off = 0;
  auto alloc = [&](size_t bytes) {
    void* p = ws + off; off += (bytes + 255) & ~(size_t)255; return p;
  };
  float* stats = (float*)alloc(768 * 4);               // [s1,q1,ssc,qsc,s2,q2] x128
  float* rtmp  = (float*)alloc(32 * 512 * 4);          // reduce stage-1 output
  u16* Xbf  = (u16*)alloc((size_t)NS * 64 * 2);
  u16* SCbf = (u16*)alloc((size_t)NS * 128 * 2);
  u16* Hbf  = (u16*)alloc((size_t)NS * 128 * 2);
  u16* Y2bf = (u16*)alloc((size_t)NS * 128 * 2);
  u16* Wp1  = (u16*)alloc((size_t)NK * 64 * 128 * 2);
  u16* Wp2  = (u16*)alloc((size_t)NK * 128 * 128 * 2);
  u16* Wpsc = (u16*)alloc((size_t)64 * 128 * 2);
  // d_out hosts y1 bf16 (51.2MB) + fused gidx (21.6MB); k_final overwrites
  u16* Y1bf = (u16*)d_out;
  int* gidx = (int*)((char*)d_out + (size_t)NS * 128 * 2);
  float* part1 = (float*)Y2bf;          // dead region until conv2
  float* part2 = (float*)Xbf;           // Xbf dead after conv1

  hipLaunchKernelGGL(k_prep_x, dim3(50000), dim3(256), 0, stream, feats, Xbf, stats);
  hipLaunchKernelGGL(k_prep_gidx, dim3((NK * NS + 255) / 256), dim3(256), 0, stream,
                     in_idx, out_idx, gidx);
  hipLaunchKernelGGL(k_pack_w, dim3(2624), dim3(256), 0, stream, W1, W2, Wsc, Wp1, Wp2, Wpsc);
  hipLaunchKernelGGL((k_conv<64, true>), dim3(NB), dim3(256), 0, stream,
                     Xbf, Wp1, Wpsc, gidx, Y1bf, SCbf, part1);
  hipLaunchKernelGGL(k_red1, dim3(2, 32), dim3(256), 0, stream, part1, rtmp, 512, NB);
  hipLaunchKernelGGL(k_red2, dim3(2), dim3(256), 0, stream, rtmp, stats, 512);
  hipLaunchKernelGGL(k_bnrelu, dim3(12500), dim3(256), 0, stream, Y1bf, stats, g1, b1, Hbf);
  hipLaunchKernelGGL((k_conv<128, false>), dim3(NB), dim3(256), 0, stream,
                     Hbf, Wp2, nullptr, gidx, Y2bf, nullptr, part2);
  hipLaunchKernelGGL(k_red1, dim3(1, 32), dim3(256), 0, stream, part2, rtmp, 256, NB);
  hipLaunchKernelGGL(k_red2, dim3(1), dim3(256), 0, stream, rtmp, stats + 512, 256);
  hipLaunchKernelGGL(k_final, dim3(25000), dim3(256), 0, stream,
                     Y2bf, SCbf, stats, g2, b2, gsc, bsc, (float*)d_out);
}